// Round 1
// baseline (181.826 us; speedup 1.0000x reference)
//
#include <hip/hip_runtime.h>
#include <hip/hip_bf16.h>

#define N_NODES 50000
#define N_EDGES 800000
#define ATOMSZ 95
#define EPSBN 1e-3f

typedef __attribute__((ext_vector_type(8))) short bf16x8;
typedef __attribute__((ext_vector_type(4))) float f32x4;

// ws layout (bytes):
//   0    : s1[128] f32
//   512  : s2[128] f32
//   1024 : bias_total[128] f32
//   2048 : Wt bf16 [128][72]  (col-major-ish: row j = output col, 72 k-slots, 64 valid)
//   20480: Ta [95][128] f32   (atom_i term + bias folded)
//   69120: Tc [95][128] f32   (atom_j term)
#define WS_WT_OFF   2048
#define WS_TA_OFF   20480
#define WS_TC_OFF   69120

__device__ __forceinline__ short f2b(float f) {
    unsigned int u = __float_as_uint(f);
    u += 0x7fffu + ((u >> 16) & 1u);   // round-to-nearest-even
    return (short)(u >> 16);
}

// ---- P1: fold BN1/BN2 into scales, compute fused bias (1 block, 128 threads)
__global__ void prep1(const float* __restrict__ W2,
                      const float* __restrict__ b1, const float* __restrict__ g1,
                      const float* __restrict__ be1, const float* __restrict__ m1,
                      const float* __restrict__ v1,
                      const float* __restrict__ b2, const float* __restrict__ g2,
                      const float* __restrict__ be2, const float* __restrict__ m2,
                      const float* __restrict__ v2,
                      float* __restrict__ ws) {
    __shared__ float c1s[128];
    int j = threadIdx.x;   // 0..127
    float s1 = g1[j] * rsqrtf(v1[j] + EPSBN);
    float c1 = (b1[j] - m1[j]) * s1 + be1[j];
    float s2 = g2[j] * rsqrtf(v2[j] + EPSBN);
    c1s[j] = c1;
    __syncthreads();
    float acc = 0.f;
    #pragma unroll 8
    for (int m = 0; m < 128; ++m) acc += c1s[m] * W2[(size_t)(128 + m) * 128 + j];
    float bias = (acc + b2[j]) * s2 + be2[j] - m2[j] * s2;
    ws[j] = s1;
    ws[128 + j] = s2;
    ws[256 + j] = bias;
}

// ---- P2: build fused bf16 weight Wt[128][72] and fp32 tables Ta/Tc[95][128]
__global__ void prep2(const float* __restrict__ W1, const float* __restrict__ W2,
                      const float* __restrict__ atab, float* __restrict__ ws) {
    const float* s1 = ws;
    const float* s2 = ws + 128;
    const float* bias = ws + 256;
    unsigned short* Wt = (unsigned short*)((char*)ws + WS_WT_OFF);
    float* Ta = (float*)((char*)ws + WS_TA_OFF);
    float* Tc = (float*)((char*)ws + WS_TC_OFF);

    int tid = blockIdx.x * 256 + threadIdx.x;
    if (tid < 128 * 72) {
        int j = tid / 72, kk = tid % 72;
        float val = 0.f;
        if (kk < 64) {
            #pragma unroll 8
            for (int m = 0; m < 128; ++m)
                val += W1[kk * 128 + m] * s1[m] * W2[(size_t)(128 + m) * 128 + j];
            val *= s2[j];
        }
        Wt[tid] = (unsigned short)f2b(val);
    } else if (tid < 128 * 72 + ATOMSZ * 128) {
        int r = tid - 128 * 72;
        int t = r / 128, j = r % 128;
        float val = 0.f;
        #pragma unroll 8
        for (int m = 0; m < 128; ++m) val += atab[t * 128 + m] * W2[(size_t)m * 128 + j];
        Ta[r] = val * s2[j] + bias[j];
    } else if (tid < 128 * 72 + 2 * ATOMSZ * 128) {
        int r = tid - 128 * 72 - ATOMSZ * 128;
        int t = r / 128, j = r % 128;
        float val = 0.f;
        #pragma unroll 8
        for (int m = 0; m < 128; ++m) val += atab[t * 128 + m] * W2[(size_t)(256 + m) * 128 + j];
        Tc[r] = val * s2[j];
    }
}

// ---- atom embedding: exact fp32 gather, 50000 x 128 (as float4)
__global__ __launch_bounds__(256) void atom_emb(const int* __restrict__ type,
                                                const float* __restrict__ atab,
                                                float* __restrict__ out) {
    int tid = blockIdx.x * 256 + threadIdx.x;   // 50000*32 = 1,600,000 exactly
    int n = tid >> 5, q = tid & 31;
    int t = type[n];
    const float4* tf = (const float4*)atab;
    ((float4*)out)[tid] = tf[t * 32 + q];
}

// ---- edge kernel: out1[e][:] = Ta[ti] + Tc[tj] + bond[e] @ Wfused  (BN2 folded)
// block = 256 threads = 4 waves, 16 edges/wave, 64 edges/block
__global__ __launch_bounds__(256) void edge_kernel(
    const float* __restrict__ bond, const int* __restrict__ ii,
    const int* __restrict__ jj, const int* __restrict__ type,
    const float* __restrict__ ws_f, float* __restrict__ out) {
    const unsigned short* WtG = (const unsigned short*)((const char*)ws_f + WS_WT_OFF);
    const float* Ta = (const float*)((const char*)ws_f + WS_TA_OFF);
    const float* Tc = (const float*)((const char*)ws_f + WS_TC_OFF);

    __shared__ unsigned short wlds[128 * 72];   // 18432 B
    {
        const unsigned int* src = (const unsigned int*)WtG;
        unsigned int* dst = (unsigned int*)wlds;
        for (int i = threadIdx.x; i < 128 * 72 / 2; i += 256) dst[i] = src[i];
    }
    __syncthreads();

    const int wave = threadIdx.x >> 6;
    const int lane = threadIdx.x & 63;
    const int arow = lane & 15;
    const int g = lane >> 4;
    const int eBase = blockIdx.x * 64 + wave * 16;

    f32x4 acc[8];
    #pragma unroll
    for (int nt = 0; nt < 8; ++nt) acc[nt] = (f32x4){0.f, 0.f, 0.f, 0.f};

    const float* aptr = bond + (size_t)(eBase + arow) * 64 + g * 8;

    #pragma unroll
    for (int s = 0; s < 2; ++s) {
        float4 f0 = *(const float4*)(aptr + s * 32);
        float4 f1 = *(const float4*)(aptr + s * 32 + 4);
        bf16x8 a;
        a[0] = f2b(f0.x); a[1] = f2b(f0.y); a[2] = f2b(f0.z); a[3] = f2b(f0.w);
        a[4] = f2b(f1.x); a[5] = f2b(f1.y); a[6] = f2b(f1.z); a[7] = f2b(f1.w);
        #pragma unroll
        for (int nt = 0; nt < 8; ++nt) {
            int col = nt * 16 + arow;
            bf16x8 b = *(const bf16x8*)&wlds[col * 72 + s * 32 + g * 8];
            acc[nt] = __builtin_amdgcn_mfma_f32_16x16x32_bf16(a, b, acc[nt], 0, 0, 0);
        }
    }

    float* outB = out + (size_t)N_NODES * 128;
    #pragma unroll
    for (int r = 0; r < 4; ++r) {
        int e = eBase + g * 4 + r;
        int ti = type[ii[e]];
        int tj = type[jj[e]];
        const float* ta = Ta + ti * 128;
        const float* tc = Tc + tj * 128;
        float* orow = outB + (size_t)e * 128;
        #pragma unroll
        for (int nt = 0; nt < 8; ++nt) {
            int col = nt * 16 + arow;
            orow[col] = acc[nt][r] + ta[col] + tc[col];
        }
    }
}

extern "C" void kernel_launch(void* const* d_in, const int* in_sizes, int n_in,
                              void* d_out, int out_size, void* d_ws, size_t ws_size,
                              hipStream_t stream) {
    const int*   atom_features = (const int*)d_in[0];
    const float* bond          = (const float*)d_in[1];
    const int*   ii            = (const int*)d_in[2];
    const int*   jj            = (const int*)d_in[3];
    const float* atab          = (const float*)d_in[4];
    const float* W1            = (const float*)d_in[5];
    const float* b1            = (const float*)d_in[6];
    const float* g1            = (const float*)d_in[7];
    const float* be1           = (const float*)d_in[8];
    const float* m1            = (const float*)d_in[9];
    const float* v1            = (const float*)d_in[10];
    const float* W2            = (const float*)d_in[11];
    const float* b2            = (const float*)d_in[12];
    const float* g2            = (const float*)d_in[13];
    const float* be2           = (const float*)d_in[14];
    const float* m2            = (const float*)d_in[15];
    const float* v2            = (const float*)d_in[16];
    float* out = (float*)d_out;
    float* ws  = (float*)d_ws;

    prep1<<<1, 128, 0, stream>>>(W2, b1, g1, be1, m1, v1, b2, g2, be2, m2, v2, ws);

    int prep2_items = 128 * 72 + 2 * ATOMSZ * 128;
    prep2<<<(prep2_items + 255) / 256, 256, 0, stream>>>(W1, W2, atab, ws);

    atom_emb<<<(N_NODES * 32) / 256, 256, 0, stream>>>(atom_features, atab, out);

    edge_kernel<<<N_EDGES / 64, 256, 0, stream>>>(bond, ii, jj, atom_features, ws, out);
}

// Round 3
// 109.044 us; speedup vs baseline: 1.6675x; 1.6675x over previous
//
#include <hip/hip_runtime.h>

#define N_NODES 50000
#define N_EDGES 800000
#define ATOMSZ 95
#define EPSBN 1e-3f
#define PREP_BLOCKS 131
#define EMB_BLOCKS 6250

typedef __attribute__((ext_vector_type(8))) short bf16x8;
typedef __attribute__((ext_vector_type(4))) float f32x4;
typedef __attribute__((ext_vector_type(4))) unsigned int u32x4;

// ws layout (bytes):
//   0     : Wt bf16 [128][72]   (row j = output col, 72 k-slots, 64 valid)
//   18432 : Ta [95][128] f32    (atom_i term + fused bias)
//   67072 : Tc [95][128] f32    (atom_j term)
#define WS_WT_OFF 0
#define WS_TA_OFF 18432
#define WS_TC_OFF 67072

__device__ __forceinline__ short f2b(float f) {
    unsigned int u = __float_as_uint(f);
    u += 0x7fffu + ((u >> 16) & 1u);   // round-to-nearest-even
    return (short)(u >> 16);
}

// ---- fused prep (blocks 0..130) + atom embedding gather (blocks 131..6380)
__global__ __launch_bounds__(256) void prep_emb(
    const int* __restrict__ type, const float* __restrict__ atab,
    const float* __restrict__ W1, const float* __restrict__ W2,
    const float* __restrict__ b1, const float* __restrict__ g1,
    const float* __restrict__ be1, const float* __restrict__ m1,
    const float* __restrict__ v1,
    const float* __restrict__ b2, const float* __restrict__ g2,
    const float* __restrict__ be2, const float* __restrict__ m2,
    const float* __restrict__ v2,
    float* __restrict__ ws, float* __restrict__ out)
{
    int blk = blockIdx.x;
    if (blk >= PREP_BLOCKS) {
        // atom embedding: exact fp32 gather, 50000 rows x 32 float4
        int tid = (blk - PREP_BLOCKS) * 256 + threadIdx.x;   // < 1,600,000
        int n = tid >> 5, q = tid & 31;
        int t = type[n];
        f32x4 v = ((const f32x4*)atab)[t * 32 + q];
        __builtin_nontemporal_store(v, ((f32x4*)out) + tid);
        return;
    }
    __shared__ float s1s[128], s2s[128], c1s[128], biass[128];
    int tj = threadIdx.x;
    if (tj < 128) {
        float s1 = g1[tj] * rsqrtf(v1[tj] + EPSBN);
        float s2 = g2[tj] * rsqrtf(v2[tj] + EPSBN);
        s1s[tj] = s1; s2s[tj] = s2;
        c1s[tj] = (b1[tj] - m1[tj]) * s1 + be1[tj];
    }
    __syncthreads();
    if (tj < 128) {
        float acc = 0.f;
        #pragma unroll 8
        for (int m = 0; m < 128; ++m) acc += c1s[m] * W2[(size_t)(128 + m) * 128 + tj];
        biass[tj] = (acc + b2[tj]) * s2s[tj] + be2[tj] - m2[tj] * s2s[tj];
    }
    __syncthreads();

    unsigned short* Wt = (unsigned short*)((char*)ws + WS_WT_OFF);
    float* Ta = (float*)((char*)ws + WS_TA_OFF);
    float* Tc = (float*)((char*)ws + WS_TC_OFF);
    int tid = blk * 256 + threadIdx.x;
    if (tid < 9216) {                       // Wt: 128 j x 72 kk
        int j = tid & 127, kk = tid >> 7;   // kk wave-uniform -> W1 reads are s_loads
        float val = 0.f;
        if (kk < 64) {
            #pragma unroll 8
            for (int m = 0; m < 128; ++m)
                val += W1[kk * 128 + m] * s1s[m] * W2[(size_t)(128 + m) * 128 + j];
            val *= s2s[j];
        }
        Wt[j * 72 + kk] = (unsigned short)f2b(val);
    } else if (tid < 9216 + 12160) {        // Ta: 95 x 128
        int r = tid - 9216;
        int t = r >> 7, j = r & 127;
        float val = 0.f;
        #pragma unroll 8
        for (int m = 0; m < 128; ++m) val += atab[t * 128 + m] * W2[(size_t)m * 128 + j];
        Ta[r] = val * s2s[j] + biass[j];
    } else {                                 // Tc: 95 x 128  (tid < 33536 exactly)
        int r = tid - 9216 - 12160;
        int t = r >> 7, j = r & 127;
        float val = 0.f;
        #pragma unroll 8
        for (int m = 0; m < 128; ++m) val += atab[t * 128 + m] * W2[(size_t)(256 + m) * 128 + j];
        Tc[r] = val * s2s[j];
    }
}

// ---- edge kernel: out1[e][:] = Ta[ti] + Tc[tj] + bond[e] @ Wfused
// block = 256 threads = 4 waves, 16 edges/wave, 64 edges/block
__global__ __launch_bounds__(256) void edge_kernel(
    const float* __restrict__ bond, const int* __restrict__ ii,
    const int* __restrict__ jj, const int* __restrict__ type,
    const float* __restrict__ ws_f, float* __restrict__ out)
{
    __shared__ char smem[33280];
    unsigned short* wlds = (unsigned short*)smem;      // 18432 B (W staging)
    float* olds = (float*)smem;                        // 32768 B (out staging, reused)
    int* tis = (int*)(smem + 32768);                   // 64 ints
    int* tjs = (int*)(smem + 32768 + 256);             // 64 ints

    const unsigned short* WtG = (const unsigned short*)((const char*)ws_f + WS_WT_OFF);
    const int eB = blockIdx.x * 64;

    {   // stage W (16B vector copies) + pre-gather per-edge atom types
        const u32x4* src = (const u32x4*)WtG;
        u32x4* dst = (u32x4*)wlds;
        #pragma unroll
        for (int i = threadIdx.x; i < 1152; i += 256) dst[i] = src[i];
        if (threadIdx.x < 64) tis[threadIdx.x] = type[ii[eB + threadIdx.x]];
        else if (threadIdx.x < 128) tjs[threadIdx.x - 64] = type[jj[eB + threadIdx.x - 64]];
    }
    __syncthreads();

    const int wave = threadIdx.x >> 6;
    const int lane = threadIdx.x & 63;
    const int arow = lane & 15;
    const int g = lane >> 4;

    f32x4 acc[8];
    #pragma unroll
    for (int nt = 0; nt < 8; ++nt) acc[nt] = (f32x4){0.f, 0.f, 0.f, 0.f};

    const float* aptr = bond + (size_t)(eB + wave * 16 + arow) * 64 + g * 8;

    #pragma unroll
    for (int s = 0; s < 2; ++s) {
        f32x4 f0 = *(const f32x4*)(aptr + s * 32);
        f32x4 f1 = *(const f32x4*)(aptr + s * 32 + 4);
        bf16x8 a;
        a[0] = f2b(f0.x); a[1] = f2b(f0.y); a[2] = f2b(f0.z); a[3] = f2b(f0.w);
        a[4] = f2b(f1.x); a[5] = f2b(f1.y); a[6] = f2b(f1.z); a[7] = f2b(f1.w);
        #pragma unroll
        for (int nt = 0; nt < 8; ++nt) {
            int col = nt * 16 + arow;
            bf16x8 b = *(const bf16x8*)&wlds[col * 72 + s * 32 + g * 8];
            acc[nt] = __builtin_amdgcn_mfma_f32_16x16x32_bf16(a, b, acc[nt], 0, 0, 0);
        }
    }
    __syncthreads();   // all waves done reading wlds -> safe to overwrite with olds

    // scatter acc into LDS, XOR-swizzled so each store instr is 2-way (free)
    {
        const int elb = wave * 16 + g * 4;
        #pragma unroll
        for (int r = 0; r < 4; ++r) {
            const int el = elb + r;
            const int mask = (el & 7) << 2;
            #pragma unroll
            for (int nt = 0; nt < 8; ++nt) {
                int col = nt * 16 + arow;
                olds[el * 128 + (col ^ mask)] = acc[nt][r];
            }
        }
    }
    __syncthreads();

    // coalesced readback: + Ta[ti] + Tc[tj], nontemporal float4 store
    const f32x4* TaV = (const f32x4*)((const char*)ws_f + WS_TA_OFF);
    const f32x4* TcV = (const f32x4*)((const char*)ws_f + WS_TC_OFF);
    float* outB = out + (size_t)N_NODES * 128;
    const int q = threadIdx.x & 31;
    const int rsub = threadIdx.x >> 5;
    #pragma unroll
    for (int p = 0; p < 8; ++p) {
        int row = p * 8 + rsub;
        f32x4 v = *(const f32x4*)&olds[row * 128 + 4 * (q ^ (row & 7))];
        int ti = tis[row], tjv = tjs[row];
        f32x4 ta = TaV[ti * 32 + q];
        f32x4 tc = TcV[tjv * 32 + q];
        v += ta + tc;
        __builtin_nontemporal_store(v, (f32x4*)&outB[(size_t)(eB + row) * 128 + q * 4]);
    }
}

extern "C" void kernel_launch(void* const* d_in, const int* in_sizes, int n_in,
                              void* d_out, int out_size, void* d_ws, size_t ws_size,
                              hipStream_t stream) {
    const int*   atom_features = (const int*)d_in[0];
    const float* bond          = (const float*)d_in[1];
    const int*   ii            = (const int*)d_in[2];
    const int*   jj            = (const int*)d_in[3];
    const float* atab          = (const float*)d_in[4];
    const float* W1            = (const float*)d_in[5];
    const float* b1            = (const float*)d_in[6];
    const float* g1            = (const float*)d_in[7];
    const float* be1           = (const float*)d_in[8];
    const float* m1            = (const float*)d_in[9];
    const float* v1            = (const float*)d_in[10];
    const float* W2            = (const float*)d_in[11];
    const float* b2            = (const float*)d_in[12];
    const float* g2            = (const float*)d_in[13];
    const float* be2           = (const float*)d_in[14];
    const float* m2            = (const float*)d_in[15];
    const float* v2            = (const float*)d_in[16];
    float* out = (float*)d_out;
    float* ws  = (float*)d_ws;

    prep_emb<<<PREP_BLOCKS + EMB_BLOCKS, 256, 0, stream>>>(
        atom_features, atab, W1, W2, b1, g1, be1, m1, v1,
        b2, g2, be2, m2, v2, ws, out);

    edge_kernel<<<N_EDGES / 64, 256, 0, stream>>>(bond, ii, jj, atom_features, ws, out);
}